// Round 10
// baseline (128.498 us; speedup 1.0000x reference)
//
#include <hip/hip_runtime.h>

typedef unsigned short u16;
typedef short bf16x8 __attribute__((ext_vector_type(8)));
typedef float f32x4 __attribute__((ext_vector_type(4)));
typedef u16 u16x4 __attribute__((ext_vector_type(4)));

__device__ __forceinline__ float b2f(u16 h) {
  unsigned u = ((unsigned)h) << 16;
  return __builtin_bit_cast(float, u);
}
// native RTNE f32->bf16; compiler pairs these into v_cvt_pk_bf16_f32
__device__ __forceinline__ u16 f2b(float f) {
  return __builtin_bit_cast(u16, (__bf16)f);
}
__device__ __forceinline__ void gld_lds16(const void* g, void* l) {
  __builtin_amdgcn_global_load_lds(
      (__attribute__((address_space(1))) void*)(g),
      (__attribute__((address_space(3))) void*)(l), 16, 0, 0);
}

// ---------------------------------------------------------------------------
// prep (unchanged): blocks [0,160): fp32 weights -> bf16 STAGED
//   [layer][s8(32)][m(256)][8]; layers: 0,1 = post_w; 2,3,4 = pre_w
// blocks [160,416): x [2][256][1024] fp32 -> xt [2048][256] bf16 (transpose)
// ---------------------------------------------------------------------------
__global__ void dense_edge_prep(const float* __restrict__ x,
                                const float* __restrict__ pre_w,
                                const float* __restrict__ post_w,
                                u16* __restrict__ wb, u16* __restrict__ xt) {
  const int blk = blockIdx.x;
  const int t = threadIdx.x;
  if (blk < 160) {
    const int id = blk * 256 + t;      // 40960 slots of 8 elems
    const int layer = id >> 13;        // 0..4
    const int sid = id & 8191;
    const int m = sid >> 5;
    const int s8 = sid & 31;
    const float* src = (layer < 2) ? (post_w + layer * 65536)
                                   : (pre_w + (layer - 2) * 65536);
    u16* dst = wb + layer * 65536;
    f32x4 a = *(const f32x4*)(src + m * 256 + s8 * 8);
    f32x4 c = *(const f32x4*)(src + m * 256 + s8 * 8 + 4);
    bf16x8 o;
#pragma unroll
    for (int j = 0; j < 4; j++) o[j] = (short)f2b(a[j]);
#pragma unroll
    for (int j = 0; j < 4; j++) o[4 + j] = (short)f2b(c[j]);
    *(bf16x8*)(dst + (s8 * 256 + m) * 8) = o;
  } else {
    __shared__ float tile[32 * 65];
    const int xb = blk - 160;          // 2 b x 8 ctile x 16 hwtile = 256
    const int b = xb >> 7;
    const int ct = (xb >> 4) & 7;
    const int ht = xb & 15;
    const int c0 = ct * 32, hw0 = ht * 64;
#pragma unroll
    for (int rep = 0; rep < 8; rep++) {
      const int idx = rep * 256 + t;
      const int cl = idx >> 6, hl = idx & 63;
      tile[cl * 65 + hl] = x[(b * 256 + c0 + cl) * 1024 + hw0 + hl];
    }
    __syncthreads();
    const int hl = t >> 2, c8 = t & 3;
    bf16x8 o;
#pragma unroll
    for (int i = 0; i < 8; i++) o[i] = (short)f2b(tile[(c8 * 8 + i) * 65 + hl]);
    *(bf16x8*)(xt + (b * 1024 + hw0 + hl) * 256 + c0 + c8 * 8) = o;
  }
}

// ---------------------------------------------------------------------------
// pre v2 (unchanged): 256 blocks x 8 nodes; garbage cols discarded by guards.
// ---------------------------------------------------------------------------
__global__ __launch_bounds__(256, 2) void dense_edge_pre(
    const u16* __restrict__ xt, const u16* __restrict__ wpre,
    const float* __restrict__ preb, u16* __restrict__ flat) {
  __shared__ u16 feat[2][2112];  // [32 s8][8 n][8] + 64 pad for col-overread
  const int t = threadIdx.x;
  const int wv = t >> 6, ln = t & 63;
  const int nb = blockIdx.x * 8;
  const int q4 = ln >> 4, r15 = ln & 15;

  {
    const int s8 = t >> 3, nl = t & 7;
    gld_lds16(xt + (nb + nl) * 256 + s8 * 8, &feat[0][t * 8]);
  }
  __syncthreads();

#pragma unroll
  for (int l = 0; l < 3; l++) {
    const u16* wl = wpre + l * 65536;
    f32x4 acc[4];
    f32x4 zero = {0.f, 0.f, 0.f, 0.f};
#pragma unroll
    for (int mt = 0; mt < 4; mt++) acc[mt] = zero;
#pragma unroll
    for (int s = 0; s < 8; s++) {
      bf16x8 bv = *(const bf16x8*)(&feat[l & 1][((s * 4 + q4) * 8 + r15) * 8]);
#pragma unroll
      for (int mt = 0; mt < 4; mt++) {
        bf16x8 av = *(const bf16x8*)(wl + ((s * 4 + q4) * 256 + wv * 64 + mt * 16 + r15) * 8);
        acc[mt] = __builtin_amdgcn_mfma_f32_16x16x32_bf16(av, bv, acc[mt], 0, 0, 0);
      }
    }
    if (l < 2) {
#pragma unroll
      for (int mt = 0; mt < 4; mt++) {
        const int o = wv * 64 + mt * 16 + q4 * 4;
        f32x4 bb = *(const f32x4*)(preb + l * 256 + o);
        u16x4 pk;
#pragma unroll
        for (int r = 0; r < 4; r++) {
          float v = fmaxf(acc[mt][r] + bb[r], 0.f);
          pk[r] = f2b(v);
        }
        if (r15 < 8)
          *(u16x4*)(&feat[(l + 1) & 1][((o >> 3) * 8 + r15) * 8 + (o & 7)]) = pk;
      }
      __syncthreads();
    } else {
#pragma unroll
      for (int mt = 0; mt < 4; mt++) {
        const int o = wv * 64 + mt * 16 + q4 * 4;
        f32x4 bb = *(const f32x4*)(preb + 512 + o);
        u16x4 pk;
#pragma unroll
        for (int r = 0; r < 4; r++) pk[r] = f2b(acc[mt][r] + bb[r]);  // no relu
        if (r15 < 8) *(u16x4*)(flat + (nb + r15) * 256 + o) = pk;
      }
    }
  }
}

// ---------------------------------------------------------------------------
// main v8: ROLE-SPLIT REGISTERS + SINGLE-BARRIER PIPELINE.
// Waves 0-3 hold ALL of W1 (af_w[4][8]=128 regs, R2-proven), waves 4-7 all
// of W2. Per iter: producers [q-gld(j+2) | G1(j)->t1[j&1] | XX(j+1)];
// consumers [out(j-2) | G2(j-1)+W3 -> pbuf[(j-1)&1]]; ONE barrier.
// wv%4 SIMD mapping pairs one producer + one consumer per SIMD -> 256
// MFMA/SIMD/iter in two independent 128-clusters; B-fragment LDS traffic
// halves vs symmetric v5-v7 (each B tile read by 4 waves, not 8).
// ---------------------------------------------------------------------------
#define NT 8  // tiles per block
__global__ __launch_bounds__(512, 2) void dense_edge_main(
    const u16* __restrict__ flat, const int* __restrict__ pidx,
    const int* __restrict__ cidx, const u16* __restrict__ w1s,
    const u16* __restrict__ w2s, const float* __restrict__ b1,
    const float* __restrict__ b2, const float* __restrict__ w3,
    const float* __restrict__ b3, float* __restrict__ out) {
  __shared__ u16 xxbuf[2][16384];    // [par][cc(32)][n(64)][8]  64 KB
  __shared__ u16 t1buf[2][16384];    // same layout              64 KB
  __shared__ u16 pstage[2048];       // p-rows [cc(32)][row(8)][8] 4 KB
  __shared__ u16 qstage[2][2048];    // q-rows dbuf                8 KB
  __shared__ float pbuf[2][4][2][64];// [par][cw][o3][edge]        4 KB

  const int t = threadIdx.x;
  const int wv = t >> 6;
  const int ln = t & 63;
  const int q4 = ln >> 4, r15 = ln & 15;
  const bool prod = wv < 4;
  const int cw = wv & 3;
  const int blk = blockIdx.x;
  const int tile0 = blk * NT;
  const int b = tile0 >> 10;
  const int pt = (tile0 >> 5) & 31;
  const int qt0 = tile0 & 31;
  const int p0 = pt * 8;

  // role weights: full 256 rows of W1 (producers) or W2 (consumers)
  const u16* wsrc = prod ? w1s : w2s;
  bf16x8 af_w[4][8];
#pragma unroll
  for (int s = 0; s < 8; s++)
#pragma unroll
    for (int mt = 0; mt < 4; mt++)
      af_w[mt][s] = *(const bf16x8*)(wsrc + ((s * 4 + q4) * 256 + cw * 64 + mt * 16 + r15) * 8);

  // init staging: producers -> pstage (+preload q indices), consumers -> qstage[0]
  const int slot4 = cw * 64 + ln;
  const int srow = slot4 & 7, scc = slot4 >> 3;
  int qn_pro = 0, qn_cur = 0;
  if (prod) {
    const int pn = pidx[b * 256 + p0 + srow];
    gld_lds16(flat + pn * 256 + scc * 8, &pstage[slot4 * 8]);
    qn_pro = cidx[b * 256 + (qt0 + 1) * 8 + srow];
    qn_cur = cidx[b * 256 + (qt0 + 2) * 8 + srow];
  } else {
    const int qn = cidx[b * 256 + qt0 * 8 + srow];
    gld_lds16(flat + qn * 256 + scc * 8, &qstage[0][slot4 * 8]);
  }
  __syncthreads();

  const int prow = ln >> 3, qrow = ln & 7;

  // ---- producer: XX build, 8 cc-chunks per wave ----
  auto do_xx = [&](int jx) {
    const u16* qs = qstage[jx & 1];
    u16* xb = xxbuf[jx & 1];
#pragma unroll
    for (int i = 0; i < 8; i++) {
      const int cc = cw * 8 + i;
      bf16x8 av = *(const bf16x8*)(&pstage[(cc * 8 + prow) * 8]);
      bf16x8 bv = *(const bf16x8*)(&qs[(cc * 8 + qrow) * 8]);
      bf16x8 ov;
#pragma unroll
      for (int jj = 0; jj < 8; jj++) {
        float d = b2f((u16)av[jj]) - b2f((u16)bv[jj]);
        ov[jj] = (short)f2b(d * d);
      }
      *(bf16x8*)(&xb[(cc * 64 + ln) * 8]) = ov;
    }
  };

  // ---- producer: GEMM1 (128 MFMA) + relu/b1 pack -> t1buf ----
  auto do_g1 = [&](int jg) {
    const u16* xb = xxbuf[jg & 1];
    f32x4 acc[4][4];
    {
      f32x4 zero = {0.f, 0.f, 0.f, 0.f};
#pragma unroll
      for (int mt = 0; mt < 4; mt++)
#pragma unroll
        for (int nt = 0; nt < 4; nt++) acc[mt][nt] = zero;
    }
    __builtin_amdgcn_s_setprio(1);
#pragma unroll
    for (int s = 0; s < 8; s++) {
      bf16x8 bfr[4];
#pragma unroll
      for (int nt = 0; nt < 4; nt++)
        bfr[nt] = *(const bf16x8*)(xb + ((s * 4 + q4) * 64 + nt * 16 + r15) * 8);
#pragma unroll
      for (int mt = 0; mt < 4; mt++)
#pragma unroll
        for (int nt = 0; nt < 4; nt++)
          acc[mt][nt] = __builtin_amdgcn_mfma_f32_16x16x32_bf16(af_w[mt][s], bfr[nt], acc[mt][nt], 0, 0, 0);
    }
    __builtin_amdgcn_s_setprio(0);
#pragma unroll
    for (int mt = 0; mt < 4; mt++) {
      const int o = cw * 64 + mt * 16 + q4 * 4;
      f32x4 bb = *(const f32x4*)(b1 + o);
#pragma unroll
      for (int nt = 0; nt < 4; nt++) {
        const int nn = nt * 16 + r15;
        u16x4 pk;
#pragma unroll
        for (int r = 0; r < 4; r++) {
          float v = fmaxf(acc[mt][nt][r] + bb[r], 0.f);
          pk[r] = f2b(v);
        }
        *(u16x4*)(&t1buf[jg & 1][((o >> 3) * 64 + nn) * 8 + (o & 7)]) = pk;
      }
    }
  };

  // ---- consumer: GEMM2 (128 MFMA) + W3 epilogue -> pbuf ----
  auto do_g2 = [&](int jg) {
    const u16* tb = t1buf[jg & 1];
    f32x4 acc[4][4];
    {
      f32x4 zero = {0.f, 0.f, 0.f, 0.f};
#pragma unroll
      for (int mt = 0; mt < 4; mt++)
#pragma unroll
        for (int nt = 0; nt < 4; nt++) acc[mt][nt] = zero;
    }
    __builtin_amdgcn_s_setprio(1);
#pragma unroll
    for (int s = 0; s < 8; s++) {
      bf16x8 bfr[4];
#pragma unroll
      for (int nt = 0; nt < 4; nt++)
        bfr[nt] = *(const bf16x8*)(tb + ((s * 4 + q4) * 64 + nt * 16 + r15) * 8);
#pragma unroll
      for (int mt = 0; mt < 4; mt++)
#pragma unroll
        for (int nt = 0; nt < 4; nt++)
          acc[mt][nt] = __builtin_amdgcn_mfma_f32_16x16x32_bf16(af_w[mt][s], bfr[nt], acc[mt][nt], 0, 0, 0);
    }
    __builtin_amdgcn_s_setprio(0);
    float part[2][4] = {{0.f, 0.f, 0.f, 0.f}, {0.f, 0.f, 0.f, 0.f}};
#pragma unroll
    for (int mt = 0; mt < 4; mt++) {
      const int o = cw * 64 + mt * 16 + q4 * 4;
      f32x4 bb = *(const f32x4*)(b2 + o);
      f32x4 w3a = *(const f32x4*)(w3 + o);
      f32x4 w3b = *(const f32x4*)(w3 + 256 + o);
#pragma unroll
      for (int nt = 0; nt < 4; nt++) {
#pragma unroll
        for (int r = 0; r < 4; r++) {
          float v = fmaxf(acc[mt][nt][r] + bb[r], 0.f);
          part[0][nt] += v * w3a[r];
          part[1][nt] += v * w3b[r];
        }
      }
    }
#pragma unroll
    for (int o3 = 0; o3 < 2; o3++)
#pragma unroll
      for (int nt = 0; nt < 4; nt++) {
        part[o3][nt] += __shfl_xor(part[o3][nt], 16, 64);
        part[o3][nt] += __shfl_xor(part[o3][nt], 32, 64);
      }
    if (q4 == 0) {
#pragma unroll
      for (int o3 = 0; o3 < 2; o3++)
#pragma unroll
        for (int nt = 0; nt < 4; nt++)
          pbuf[jg & 1][cw][o3][nt * 16 + r15] = part[o3][nt];
    }
  };

  // prologue: producers build XX(0), issue q-gather for tile 1
  if (prod) {
    do_xx(0);
    gld_lds16(flat + qn_pro * 256 + scc * 8, &qstage[1][slot4 * 8]);
  }
  __syncthreads();

#pragma unroll 1
  for (int j = 0; j <= NT; j++) {
    if (prod) {
      // q-gather for tile j+2 first (lands under G1's MFMA cluster)
      if (j < NT - 2) {
        gld_lds16(flat + qn_cur * 256 + scc * 8, &qstage[j & 1][slot4 * 8]);
        if (j < NT - 3) qn_cur = cidx[b * 256 + (qt0 + j + 3) * 8 + srow];
      }
      if (j < NT) do_g1(j);
      if (j < NT - 1) do_xx(j + 1);
    } else {
      // out(j-2) store at top (drains under G2's MFMA cluster)
      if (j >= 2) {
        const int jo = j - 2;
        const int tt = t & 255;
        if (tt < 128) {
          const int o3 = tt >> 6;
          const int n = tt & 63;
          float v = b3[o3];
#pragma unroll
          for (int k = 0; k < 4; k++) v += pbuf[jo & 1][k][o3][n];
          out[((b * 2 + o3) * 256 + p0 + (n >> 3)) * 256 + (qt0 + jo) * 8 + (n & 7)] = v;
        }
      }
      if (j > 0) do_g2(j - 1);
    }
    __syncthreads();
  }

  // epilogue: out(NT-1) by consumers
  if (!prod) {
    const int jo = NT - 1;
    const int tt = t & 255;
    if (tt < 128) {
      const int o3 = tt >> 6;
      const int n = tt & 63;
      float v = b3[o3];
#pragma unroll
      for (int k = 0; k < 4; k++) v += pbuf[jo & 1][k][o3][n];
      out[((b * 2 + o3) * 256 + p0 + (n >> 3)) * 256 + (qt0 + jo) * 8 + (n & 7)] = v;
    }
  }
}

// ---------------------------------------------------------------------------
extern "C" void kernel_launch(void* const* d_in, const int* in_sizes, int n_in,
                              void* d_out, int out_size, void* d_ws, size_t ws_size,
                              hipStream_t stream) {
  (void)in_sizes; (void)n_in; (void)out_size; (void)ws_size;
  const float* x          = (const float*)d_in[0];
  const int*   pidx       = (const int*)d_in[1];
  const int*   cidx       = (const int*)d_in[2];
  const float* pre_w      = (const float*)d_in[3];
  const float* pre_b      = (const float*)d_in[4];
  const float* post_w     = (const float*)d_in[5];
  const float* post_b     = (const float*)d_in[6];
  const float* post_out_w = (const float*)d_in[7];
  const float* post_out_b = (const float*)d_in[8];
  float* out = (float*)d_out;

  u16* ws   = (u16*)d_ws;
  u16* wb   = ws;              // staged bf16 weights: w1,w2,pre0,pre1,pre2
  u16* w1s  = wb;
  u16* w2s  = wb + 65536;
  u16* wpre = wb + 131072;
  u16* xt   = ws + 327680;     // x_t bf16 [2048][256]
  u16* flat = ws + 851968;     // node features bf16 [2048][256]

  dense_edge_prep<<<416, 256, 0, stream>>>(x, pre_w, post_w, wb, xt);
  dense_edge_pre<<<256, 256, 0, stream>>>(xt, wpre, pre_b, flat);
  dense_edge_main<<<256, 512, 0, stream>>>(flat, pidx, cidx, w1s, w2s,
                                           post_b, post_b + 256,
                                           post_out_w, post_out_b, out);
}